// Round 2
// baseline (285.448 us; speedup 1.0000x reference)
//
#include <hip/hip_runtime.h>
#include <hip/hip_bf16.h>
#include <math.h>

#define B 4
#define A 256
#define NN 64
#define NCB 128
#define NF 128
#define NSB 50
#define BA (B*A)
#define PAIRS (BA*NN)

typedef __bf16 bf;
typedef __attribute__((ext_vector_type(8))) __bf16 bfrag8;
typedef __attribute__((ext_vector_type(4))) float ffrag4;

// ---- module-scope scratch (never touches inputs / d_ws) ----
__device__ __attribute__((aligned(16))) bf    g_yib[BA*NF];          // bf16(xi @ in2f_W)
__device__ __attribute__((aligned(16))) bf    g_vij[(size_t)PAIRS*NCB]; // bf16 vij stash (16 MB)
__device__ __attribute__((aligned(16))) float g_vik[BA*NCB*3];       // fp32 Vik rows [ba][c*3+d]
// transposed bf16 weights, layout [n][k] (k contiguous, all padded to K=128)
__device__ __attribute__((aligned(16))) bf g_tf1[NF*128];
__device__ __attribute__((aligned(16))) bf g_tf2[NF*NF];
__device__ __attribute__((aligned(16))) bf g_tfo[NF*NF];
__device__ __attribute__((aligned(16))) bf g_tp1[NF*NF];
__device__ __attribute__((aligned(16))) bf g_tp2[NF*NF];
__device__ __attribute__((aligned(16))) bf g_te1[NF*NF];
__device__ __attribute__((aligned(16))) bf g_te2[NF*NF];

// fast ssp: softplus(x)-ln2 via hw v_exp_f32/v_log_f32
__device__ __forceinline__ float ssp(float x){
    float e = __expf(-fabsf(x));
    return fmaxf(x, 0.f) + __logf(1.f + e) - 0.6931471805599453f;
}

// ---- weight pre-transpose: W[k][n] fp32 -> Wt[n][k] bf16, K padded to 128 ----
__global__ __launch_bounds__(256)
void k_wt(const float* __restrict__ f1, const float* __restrict__ f2,
          const float* __restrict__ fo, const float* __restrict__ p1,
          const float* __restrict__ p2, const float* __restrict__ e1,
          const float* __restrict__ e2){
    int s = blockIdx.x >> 3, part = blockIdx.x & 7;
    const float* src = (s==0)?f1:(s==1)?f2:(s==2)?fo:(s==3)?p1:(s==4)?p2:(s==5)?e1:e2;
    bf* dst = (s==0)?g_tf1:(s==1)?g_tf2:(s==2)?g_tfo:(s==3)?g_tp1:(s==4)?g_tp2:(s==5)?g_te1:g_te2;
    int realK = (s==0) ? NSB : 128;
    int base = part*2048;                         // 16384 elems per matrix / 8 parts
    for (int e = base + threadIdx.x; e < base + 2048; e += 256){
        int n = e >> 7, k = e & 127;
        dst[e] = (k < realK) ? (bf)src[k*NF + n] : (bf)0.f;
    }
}

// ---- g_yib[row][f] = bf16( xi[row,:] @ in2f_W[:,f] ) ----
__global__ __launch_bounds__(NF)
void k_yi(const float* __restrict__ xi, const float* __restrict__ W){
    int row = blockIdx.x, f = threadIdx.x;
    __shared__ float x[NCB];
    x[f] = xi[row*NCB + f];
    __syncthreads();
    float s = 0.f;
    #pragma unroll 16
    for (int c = 0; c < NCB; c++) s += x[c]*W[c*NF + f];
    g_yib[row*NF + f] = (bf)s;
}

// ---- async-stage helpers: global->reg (issue early), reg->LDS (write late) ----
__device__ __forceinline__ void wload(bfrag8 r[4], const bf* __restrict__ g,
                                      int half, int tid){
    #pragma unroll
    for (int i = 0; i < 4; i++){
        int rr = i*16 + (tid >> 4);
        int cp = (tid & 15)*8;
        r[i] = *(const bfrag8*)&g[(half*64 + rr)*128 + cp];
    }
}
__device__ __forceinline__ void wstore(bf* __restrict__ sW, const bfrag8 r[4], int tid){
    #pragma unroll
    for (int i = 0; i < 4; i++){
        int rr = i*16 + (tid >> 4);
        int cp = (tid & 15)*8;
        *(bfrag8*)&sW[rr*136 + cp] = r[i];
    }
}
__device__ __forceinline__ void gemm4(const bf* __restrict__ sW, const bfrag8 afr[4],
                                      ffrag4 acc[4], int q, int c16){
    #pragma unroll
    for (int nt = 0; nt < 4; nt++){
        ffrag4 a = {0.f,0.f,0.f,0.f};
        #pragma unroll
        for (int kt = 0; kt < 4; kt++){
            bfrag8 bv = *(const bfrag8*)&sW[(nt*16 + c16)*136 + kt*32 + q*8];
            a = __builtin_amdgcn_mfma_f32_16x16x32_bf16(afr[kt], bv, a, 0, 0, 0);
        }
        acc[nt] = a;
    }
}

#define RDA(SRC) { _Pragma("unroll") for (int kt = 0; kt < 4; kt++) \
    afr[kt] = *(const bfrag8*)&SRC[arow*136 + kt*32 + q*8]; }

// epilogue macros (H = half of current stage)
#define EPI_SSP(DST, BIASP, H) \
    { _Pragma("unroll") for (int nt = 0; nt < 4; nt++){ \
        int col = ((H)*4 + nt)*16 + c16; \
        float bias = BIASP[col]; \
        _Pragma("unroll") for (int rg = 0; rg < 4; rg++){ \
            int row = w*16 + q*4 + rg; \
            DST[row*136 + col] = (bf)ssp(acc[nt][rg] + bias); \
        } } }

#define EPI_LIN(DST, BIASP, H) \
    { _Pragma("unroll") for (int nt = 0; nt < 4; nt++){ \
        int col = ((H)*4 + nt)*16 + c16; \
        float bias = BIASP[col]; \
        _Pragma("unroll") for (int rg = 0; rg < 4; rg++){ \
            int row = w*16 + q*4 + rg; \
            DST[row*136 + col] = (bf)(acc[nt][rg] + bias); \
        } } }

__global__ __launch_bounds__(256, 3)
void k_main(const float* __restrict__ r_ij, const float* __restrict__ cos_ij,
            const float* __restrict__ f_ij, const float* __restrict__ mask,
            const int* __restrict__ neighbors,
            const float* __restrict__ fb1, const float* __restrict__ fb2,
            const float* __restrict__ f2b,
            const float* __restrict__ aW1, const float* __restrict__ ab1,
            const float* __restrict__ aW2, const float* __restrict__ ab2,
            const float* __restrict__ pb1, const float* __restrict__ pb2,
            const float* __restrict__ eb1, const float* __restrict__ eb2,
            float* __restrict__ out_vi){
    const int tid  = threadIdx.x;
    const int ba   = blockIdx.x;          // atom (b*A + a)
    const int b    = ba >> 8;
    const int w    = tid >> 6;            // wave 0..3 -> m-tile
    const int lane = tid & 63;
    const int q    = lane >> 4;
    const int c16  = lane & 15;
    const int arow = w*16 + c16;          // A-frag row for this lane

    // sW blob doubles as finale scratch after the last gemm. 53,760 B total.
    __shared__ __attribute__((aligned(16))) char sWb[64*136*2];
    bf* const sW = (bf*)sWb;
    __shared__ __attribute__((aligned(16))) bf sA [64*136];   // h1/u/v
    __shared__ __attribute__((aligned(16))) bf sA2[64*136];   // f / hp / vij / he
    __shared__ float sCosM[64*4];   // cos0,cos1,cos2,mask
    __shared__ float sCr[64];
    __shared__ int   sJb[64];       // (b*A+j)*NF

    bfrag8 wA[4], wB[4], afr[4]; ffrag4 acc[4];

    // prefetch stage-0 weights IMMEDIATELY (latency hides under preload)
    wload(wA, g_tf1, 0, tid);

    // ---- preload: f -> sA2 (K zero-padded to 128), per-pair scalars ----
    #pragma unroll
    for (int i = 0; i < 32; i++){
        int e = tid + i*256;                       // 64 rows x 128 cols
        int row = e >> 7, col = e & 127;
        float v = (col < NSB) ? f_ij[(ba*64 + row)*NSB + col] : 0.f;
        sA2[row*136 + col] = (bf)v;
    }
    if (tid < 64){
        int p = ba*64 + tid;
        sCosM[tid*4+0] = cos_ij[p*3+0];
        sCosM[tid*4+1] = cos_ij[p*3+1];
        sCosM[tid*4+2] = cos_ij[p*3+2];
        sCosM[tid*4+3] = mask[p];
        float r = r_ij[p];
        sCr[tid] = (r < 5.f) ? 0.5f*(__cosf(r*0.62831853071795864769f) + 1.f) : 0.f;
        int j = neighbors[p] & (A-1);
        sJb[tid] = (b*A + j)*NF;
    }
    __syncthreads();

    RDA(sA2);                                   // A-frags: f (zero-padded)

    // ====== pipelined stages: {wstore cur | wload next | bar | gemm | epi | bar} ======
    // s0: tf1 h0
    wstore(sW, wA, tid); wload(wB, g_tf1, 1, tid); __syncthreads();
    gemm4(sW, afr, acc, q, c16);
    EPI_SSP(sA, fb1, 0);
    __syncthreads();
    // s1: tf1 h1
    wstore(sW, wB, tid); wload(wA, g_tf2, 0, tid); __syncthreads();
    gemm4(sW, afr, acc, q, c16);
    EPI_SSP(sA, fb1, 1);
    RDA(sA);                                    // A-frags: h1
    __syncthreads();

    // s2: tf2 h0  (Wf = (h1@fW2+fb2)*C ; u = yj*Wf)
    wstore(sW, wA, tid); wload(wB, g_tf2, 1, tid); __syncthreads();
    gemm4(sW, afr, acc, q, c16);
    #pragma unroll
    for (int nt = 0; nt < 4; nt++){
        int col = nt*16 + c16;
        float bias = fb2[col];
        #pragma unroll
        for (int rg = 0; rg < 4; rg++){
            int row = w*16 + q*4 + rg;
            float wf = (acc[nt][rg] + bias) * sCr[row];
            sA[row*136 + col] = (bf)((float)g_yib[sJb[row] + col] * wf);
        }
    }
    __syncthreads();
    // s3: tf2 h1
    wstore(sW, wB, tid); wload(wA, g_tfo, 0, tid); __syncthreads();
    gemm4(sW, afr, acc, q, c16);
    #pragma unroll
    for (int nt = 0; nt < 4; nt++){
        int col = (4 + nt)*16 + c16;
        float bias = fb2[col];
        #pragma unroll
        for (int rg = 0; rg < 4; rg++){
            int row = w*16 + q*4 + rg;
            float wf = (acc[nt][rg] + bias) * sCr[row];
            sA[row*136 + col] = (bf)((float)g_yib[sJb[row] + col] * wf);
        }
    }
    RDA(sA);                                    // A-frags: u
    __syncthreads();

    // s4: tfo h0  (v = ssp(u@f2W+f2b); vsum partials in regs)
    float vsAll[8];
    #pragma unroll
    for (int t = 0; t < 8; t++) vsAll[t] = 0.f;
    wstore(sW, wA, tid); wload(wB, g_tfo, 1, tid); __syncthreads();
    gemm4(sW, afr, acc, q, c16);
    #pragma unroll
    for (int nt = 0; nt < 4; nt++){
        int col = nt*16 + c16;
        float bias = f2b[col];
        #pragma unroll
        for (int rg = 0; rg < 4; rg++){
            int row = w*16 + q*4 + rg;
            float v = ssp(acc[nt][rg] + bias);
            sA[row*136 + col] = (bf)v;
            vsAll[nt] += v * sCosM[row*4+3];
        }
    }
    __syncthreads();
    // s5: tfo h1
    wstore(sW, wB, tid); wload(wA, g_tp1, 0, tid); __syncthreads();
    gemm4(sW, afr, acc, q, c16);
    #pragma unroll
    for (int nt = 0; nt < 4; nt++){
        int col = (4 + nt)*16 + c16;
        float bias = f2b[col];
        #pragma unroll
        for (int rg = 0; rg < 4; rg++){
            int row = w*16 + q*4 + rg;
            float v = ssp(acc[nt][rg] + bias);
            sA[row*136 + col] = (bf)v;
            vsAll[4 + nt] += v * sCosM[row*4+3];
        }
    }
    RDA(sA);                                    // A-frags: v
    __syncthreads();

    // s6: tp1 h0
    wstore(sW, wA, tid); wload(wB, g_tp1, 1, tid); __syncthreads();
    gemm4(sW, afr, acc, q, c16);
    EPI_SSP(sA2, pb1, 0);
    __syncthreads();
    // s7: tp1 h1
    wstore(sW, wB, tid); wload(wA, g_tp2, 0, tid); __syncthreads();
    gemm4(sW, afr, acc, q, c16);
    EPI_SSP(sA2, pb1, 1);
    RDA(sA2);                                   // A-frags: hp
    __syncthreads();

    // s8: tp2 h0  (vij = hp@pW2+pb2, linear)
    wstore(sW, wA, tid); wload(wB, g_tp2, 1, tid); __syncthreads();
    gemm4(sW, afr, acc, q, c16);
    EPI_LIN(sA2, pb2, 0);
    __syncthreads();
    // s9: tp2 h1
    wstore(sW, wB, tid); wload(wA, g_te1, 0, tid); __syncthreads();
    gemm4(sW, afr, acc, q, c16);
    EPI_LIN(sA2, pb2, 1);
    RDA(sA);                                    // A-frags: v (again, for env)
    __syncthreads();

    // s10: te1 h0  — first: stream vij (sA2) -> g_vij (reads all rows, pre-barrier1)
    #pragma unroll
    for (int i = 0; i < 4; i++){
        int row = i*16 + (tid >> 4);
        int cp  = (tid & 15)*8;
        *(bfrag8*)&g_vij[((size_t)ba*64 + row)*128 + cp] = *(const bfrag8*)&sA2[row*136 + cp];
    }
    wstore(sW, wA, tid); wload(wB, g_te1, 1, tid); __syncthreads();
    gemm4(sW, afr, acc, q, c16);
    EPI_SSP(sA2, eb1, 0);
    __syncthreads();
    // s11: te1 h1
    wstore(sW, wB, tid); wload(wA, g_te2, 0, tid); __syncthreads();
    gemm4(sW, afr, acc, q, c16);
    EPI_SSP(sA2, eb1, 1);
    RDA(sA2);                                   // A-frags: he
    __syncthreads();

    // s12: te2 h0  (vik ; Vik partials in regs)
    float vkAll[8][3];
    #pragma unroll
    for (int t = 0; t < 8; t++){ vkAll[t][0]=0.f; vkAll[t][1]=0.f; vkAll[t][2]=0.f; }
    wstore(sW, wA, tid); wload(wB, g_te2, 1, tid); __syncthreads();
    gemm4(sW, afr, acc, q, c16);
    #pragma unroll
    for (int nt = 0; nt < 4; nt++){
        float bias = eb2[nt*16 + c16];
        #pragma unroll
        for (int rg = 0; rg < 4; rg++){
            int row = w*16 + q*4 + rg;
            float vik = (acc[nt][rg] + bias) * sCosM[row*4+3];
            vkAll[nt][0] += vik * sCosM[row*4+0];
            vkAll[nt][1] += vik * sCosM[row*4+1];
            vkAll[nt][2] += vik * sCosM[row*4+2];
        }
    }
    __syncthreads();
    // s13: te2 h1 (last stage — no prefetch)
    wstore(sW, wB, tid); __syncthreads();
    gemm4(sW, afr, acc, q, c16);
    #pragma unroll
    for (int nt = 0; nt < 4; nt++){
        float bias = eb2[(4 + nt)*16 + c16];
        #pragma unroll
        for (int rg = 0; rg < 4; rg++){
            int row = w*16 + q*4 + rg;
            float vik = (acc[nt][rg] + bias) * sCosM[row*4+3];
            vkAll[4 + nt][0] += vik * sCosM[row*4+0];
            vkAll[4 + nt][1] += vik * sCosM[row*4+1];
            vkAll[4 + nt][2] += vik * sCosM[row*4+2];
        }
    }

    // ===== finale: all sW reads done -> barrier, reuse blob as scratch =====
    __syncthreads();
    float* const sVs   = (float*)sWb;            // 4*128 floats
    float* const sVk   = (float*)(sWb + 2048);   // 4*384 floats
    float* const sVsum = (float*)(sWb + 8192);   // 128 floats
    float* const sHa   = (float*)(sWb + 8704);   // 128 floats
    #pragma unroll
    for (int t = 0; t < 8; t++){
        float v = vsAll[t];
        v += __shfl_xor(v, 16);
        v += __shfl_xor(v, 32);
        if (q == 0) sVs[w*128 + t*16 + c16] = v;
    }
    #pragma unroll
    for (int t = 0; t < 8; t++){
        #pragma unroll
        for (int d = 0; d < 3; d++){
            float v = vkAll[t][d];
            v += __shfl_xor(v, 16);
            v += __shfl_xor(v, 32);
            if (q == 0) sVk[w*384 + (t*16 + c16)*3 + d] = v;
        }
    }
    __syncthreads();

    for (int e = tid; e < 384; e += 256)
        g_vik[ba*384 + e] = sVk[e] + sVk[384+e] + sVk[768+e] + sVk[1152+e];
    if (tid < 128)
        sVsum[tid] = sVs[tid] + sVs[128+tid] + sVs[256+tid] + sVs[384+tid];
    __syncthreads();
    if (tid < 128){
        float acc2 = ab1[tid];
        #pragma unroll 16
        for (int k = 0; k < 128; k++) acc2 += sVsum[k]*aW1[k*128 + tid];
        sHa[tid] = ssp(acc2);
    }
    __syncthreads();
    if (tid < 128){
        float acc2 = ab2[tid];
        #pragma unroll 16
        for (int k = 0; k < 128; k++) acc2 += sHa[k]*aW2[k*128 + tid];
        out_vi[ba*128 + tid] = acc2;
    }
}

// ---- V[p,c,d] = vij[p,c]*cos[p,d] + Vik[ba] + Vik[j] ----
// One block per atom, one WAVE per pair (16 pairs/wave, no barriers in loop).
// Each lane owns 2 channels -> 6 contiguous output floats -> 3x float2 stores
// (cached, so L2 merges the stride-24B lane pattern into full-line writebacks).
__global__ __launch_bounds__(256)
void k_V(const float* __restrict__ cos_ij, const int* __restrict__ nbrs,
         float* __restrict__ outV){
    const int ba   = blockIdx.x;
    const int b    = ba >> 8;
    const int tid  = threadIdx.x;
    const int w    = tid >> 6;
    const int lane = tid & 63;
    __shared__ float sVa[384];
    __shared__ float sC[64*4];
    __shared__ int   sJ[64];
    for (int e = tid; e < 384; e += 256) sVa[e] = g_vik[ba*384 + e];
    if (tid < 64){
        int p = ba*64 + tid;
        sJ[tid] = (b*A + (nbrs[p] & (A-1)))*384;
        sC[tid*4+0] = cos_ij[p*3+0];
        sC[tid*4+1] = cos_ij[p*3+1];
        sC[tid*4+2] = cos_ij[p*3+2];
    }
    __syncthreads();
    const int c0 = lane*2;                       // this lane's first channel
    const float a00=sVa[c0*3+0], a01=sVa[c0*3+1], a02=sVa[c0*3+2];
    const float a10=sVa[c0*3+3], a11=sVa[c0*3+4], a12=sVa[c0*3+5];
    #pragma unroll 4
    for (int i = 0; i < 16; i++){
        int n = w*16 + i;
        size_t p = (size_t)ba*64 + n;
        unsigned int u = *(const unsigned int*)&g_vij[p*128 + c0];  // 2 bf16
        float v0 = __uint_as_float(u << 16);
        float v1 = __uint_as_float(u & 0xffff0000u);
        float cc0 = sC[n*4+0], cc1 = sC[n*4+1], cc2 = sC[n*4+2];
        const float* vj = g_vik + sJ[n] + c0*3;
        float2 j01 = *(const float2*)(vj);
        float2 j23 = *(const float2*)(vj + 2);
        float2 j45 = *(const float2*)(vj + 4);
        float* o = outV + p*384 + c0*3;
        float2 o01 = { fmaf(v0, cc0, a00 + j01.x), fmaf(v0, cc1, a01 + j01.y) };
        float2 o23 = { fmaf(v0, cc2, a02 + j23.x), fmaf(v1, cc0, a10 + j23.y) };
        float2 o45 = { fmaf(v1, cc1, a11 + j45.x), fmaf(v1, cc2, a12 + j45.y) };
        *(float2*)(o)     = o01;
        *(float2*)(o + 2) = o23;
        *(float2*)(o + 4) = o45;
    }
}

extern "C" void kernel_launch(void* const* d_in, const int* in_sizes, int n_in,
                              void* d_out, int out_size, void* d_ws, size_t ws_size,
                              hipStream_t stream){
    const float* xi      = (const float*)d_in[0];
    const float* r_ij    = (const float*)d_in[1];
    const float* cos_ij  = (const float*)d_in[2];
    const float* f_ij    = (const float*)d_in[3];
    const float* nmask   = (const float*)d_in[4];
    const float* fW1     = (const float*)d_in[5];
    const float* fb1     = (const float*)d_in[6];
    const float* fW2     = (const float*)d_in[7];
    const float* fb2     = (const float*)d_in[8];
    const float* in2f_W  = (const float*)d_in[9];
    const float* f2W     = (const float*)d_in[10];
    const float* f2b     = (const float*)d_in[11];
    const float* aW1     = (const float*)d_in[12];
    const float* ab1     = (const float*)d_in[13];
    const float* aW2     = (const float*)d_in[14];
    const float* ab2     = (const float*)d_in[15];
    const float* pW1     = (const float*)d_in[16];
    const float* pb1     = (const float*)d_in[17];
    const float* pW2     = (const float*)d_in[18];
    const float* pb2     = (const float*)d_in[19];
    const float* eW1     = (const float*)d_in[20];
    const float* eb1     = (const float*)d_in[21];
    const float* eW2     = (const float*)d_in[22];
    const float* eb2     = (const float*)d_in[23];
    const int*  nbrs     = (const int*)d_in[24];

    float* out_vi = (float*)d_out;             // [B,A,NCB] fp32
    float* outV   = (float*)d_out + BA*NCB;    // [B,A,N,NCB,3] fp32

    k_wt<<<56, 256, 0, stream>>>(fW1, fW2, f2W, pW1, pW2, eW1, eW2);
    k_yi<<<BA, NF, 0, stream>>>(xi, in2f_W);

    k_main<<<BA, 256, 0, stream>>>(r_ij, cos_ij, f_ij, nmask, nbrs,
                                   fb1, fb2, f2b,
                                   aW1, ab1, aW2, ab2,
                                   pb1, pb2, eb1, eb2,
                                   out_vi);

    k_V<<<BA, 256, 0, stream>>>(cos_ij, nbrs, outV);
}